// Round 1
// baseline (440.080 us; speedup 1.0000x reference)
//
#include <hip/hip_runtime.h>
#include <hip/hip_bf16.h>
#include <stdint.h>

#define S_LEN  2048
#define DMODEL 2048
#define NHEADS 16
#define DHEAD  128
#define NBATCH 2
#define MROWS  (NBATCH * S_LEN)   // 4096

typedef __bf16 bf16_t;
typedef __bf16 bf16x8 __attribute__((ext_vector_type(8)));
typedef float  f32x4  __attribute__((ext_vector_type(4)));

#define MFMA_BF16(A, B, C) __builtin_amdgcn_mfma_f32_16x16x32_bf16((A), (B), (C), 0, 0, 0)

__device__ __forceinline__ void gload_lds16(const void* g, void* l) {
  __builtin_amdgcn_global_load_lds(
      (__attribute__((address_space(1))) uint32_t*)(uintptr_t)g,
      (__attribute__((address_space(3))) uint32_t*)l,
      16, 0, 0);
}

// ---------------------------------------------------------------- cast x -> bf16
__global__ __launch_bounds__(256) void cast_kernel(const float* __restrict__ X,
                                                   bf16_t* __restrict__ Xb) {
  const int i = blockIdx.x * 256 + threadIdx.x;
  const f32x4 a = ((const f32x4*)X)[2 * i];
  const f32x4 b = ((const f32x4*)X)[2 * i + 1];
  bf16x8 o;
#pragma unroll
  for (int j = 0; j < 4; ++j) { o[j] = (bf16_t)a[j]; o[j + 4] = (bf16_t)b[j]; }
  ((bf16x8*)Xb)[i] = o;
}

// ---------------------------------------------------- W [K][N] f32 -> Wt [N][K] bf16
__global__ __launch_bounds__(256) void transpose_cast(
    const float* __restrict__ W0, const float* __restrict__ W1,
    const float* __restrict__ W2, const float* __restrict__ W3,
    bf16_t* __restrict__ T0, bf16_t* __restrict__ T1,
    bf16_t* __restrict__ T2, bf16_t* __restrict__ T3) {
  const float* W; bf16_t* T;
  switch (blockIdx.z) {
    case 0:  W = W0; T = T0; break;
    case 1:  W = W1; T = T1; break;
    case 2:  W = W2; T = T2; break;
    default: W = W3; T = T3; break;
  }
  __shared__ float tile[64][65];
  const int r0 = blockIdx.y * 64;
  const int c0 = blockIdx.x * 64;
  const int tx = threadIdx.x & 63;
  const int ty = threadIdx.x >> 6;
#pragma unroll
  for (int i = 0; i < 16; ++i) {
    const int r = ty + i * 4;
    tile[r][tx] = W[(size_t)(r0 + r) * DMODEL + c0 + tx];
  }
  __syncthreads();
#pragma unroll
  for (int i = 0; i < 16; ++i) {
    const int r = ty + i * 4;
    T[(size_t)(c0 + r) * DMODEL + r0 + tx] = (bf16_t)tile[tx][r];
  }
}

// ------------------------------------------------------------------ m97-style GEMM
// A [M][2048] bf16 row-major, Bt [N=2048][K=2048] bf16 (B transposed), bias f32.
// MODE 0: bf16 out scattered to [B,H,S,D]; MODE 1: f32 out row-major [M][2048].
template <int MODE>
__device__ __forceinline__ void gemm_body(const bf16_t* __restrict__ A,
                                          const bf16_t* __restrict__ Bt,
                                          const float* __restrict__ bias,
                                          void* __restrict__ out) {
  __shared__ bf16_t lds[128 * 32 * 2];   // A tile | B tile, 8KB each
  const int tid  = threadIdx.x;
  const int lane = tid & 63;
  const int w    = tid >> 6;
  const int g    = lane >> 4;
  const int l16  = lane & 15;
  const int m0   = blockIdx.y * 128;
  const int n0   = blockIdx.x * 128;
  const int wm   = w >> 1, wn = w & 1;

  f32x4 acc[4][4];
#pragma unroll
  for (int i = 0; i < 4; ++i)
#pragma unroll
    for (int j = 0; j < 4; ++j) acc[i][j] = (f32x4){0.f, 0.f, 0.f, 0.f};

  const bf16_t* src   = (w < 2) ? A : Bt;
  const int rowbase   = (w < 2) ? m0 : n0;
  char* ldsst         = (char*)lds + (w >= 2 ? 8192 : 0);
  const char* lA      = (const char*)lds;
  const char* lB      = (const char*)lds + 8192;

  for (int kt = 0; kt < DMODEL; kt += 32) {
    // stage: waves 0,1 -> A tile, waves 2,3 -> B tile; 4 issues of 64 lanes x 16B
#pragma unroll
    for (int it = 0; it < 4; ++it) {
      const int c   = (w & 1) * 256 + it * 64 + lane;   // chunk 0..511
      const int row = c >> 2;
      const int q4  = (c & 3) ^ (row & 3);              // inverse swizzle on source
      gload_lds16(src + (size_t)(rowbase + row) * DMODEL + kt + q4 * 8,
                  ldsst + ((w & 1) * 256 + it * 64) * 16);
    }
    asm volatile("s_waitcnt vmcnt(0)" ::: "memory");
    __syncthreads();

    bf16x8 af[4], bfr[4];
#pragma unroll
    for (int i = 0; i < 4; ++i) {
      const int row = wm * 64 + i * 16 + l16;
      af[i] = *(const bf16x8*)(lA + row * 64 + ((g * 16) ^ ((row & 3) << 4)));
    }
#pragma unroll
    for (int j = 0; j < 4; ++j) {
      const int row = wn * 64 + j * 16 + l16;
      bfr[j] = *(const bf16x8*)(lB + row * 64 + ((g * 16) ^ ((row & 3) << 4)));
    }
#pragma unroll
    for (int i = 0; i < 4; ++i)
#pragma unroll
      for (int j = 0; j < 4; ++j)
        acc[i][j] = MFMA_BF16(af[i], bfr[j], acc[i][j]);
    __syncthreads();
  }

#pragma unroll
  for (int i = 0; i < 4; ++i) {
#pragma unroll
    for (int j = 0; j < 4; ++j) {
      const int n    = n0 + wn * 64 + j * 16 + l16;
      const float bb = bias[n];
#pragma unroll
      for (int r = 0; r < 4; ++r) {
        const int m   = m0 + wm * 64 + i * 16 + g * 4 + r;
        const float v = acc[i][j][r] + bb;
        if (MODE == 0) {
          const int b = m >> 11, s = m & (S_LEN - 1);
          const int h = n >> 7,  d = n & (DHEAD - 1);
          ((bf16_t*)out)[((size_t)(b * NHEADS + h) * S_LEN + s) * DHEAD + d] = (bf16_t)v;
        } else {
          ((float*)out)[(size_t)m * DMODEL + n] = v;
        }
      }
    }
  }
}

__global__ __launch_bounds__(256, 2) void gemm_qkv(
    const bf16_t* __restrict__ Xb,
    const bf16_t* __restrict__ WqT, const bf16_t* __restrict__ WkT,
    const bf16_t* __restrict__ WvT,
    const float* __restrict__ bq, const float* __restrict__ bk,
    const float* __restrict__ bv,
    bf16_t* __restrict__ Qg, bf16_t* __restrict__ Kg, bf16_t* __restrict__ Vg) {
  const bf16_t* Bt; const float* bias; bf16_t* out;
  if (blockIdx.z == 0)      { Bt = WqT; bias = bq; out = Qg; }
  else if (blockIdx.z == 1) { Bt = WkT; bias = bk; out = Kg; }
  else                      { Bt = WvT; bias = bv; out = Vg; }
  gemm_body<0>(Xb, Bt, bias, out);
}

__global__ __launch_bounds__(256, 2) void gemm_out(
    const bf16_t* __restrict__ Ctx, const bf16_t* __restrict__ WoT,
    const float* __restrict__ bo, float* __restrict__ out) {
  gemm_body<1>(Ctx, WoT, bo, out);
}

// --------------------------------------------------------------- flash attention
// Q,K,V bf16 [BH=32][S=2048][128]. Per block: one bh, 128 Q rows, 4 waves x 32 rows.
__global__ __launch_bounds__(256, 2) void attn_kernel(
    const bf16_t* __restrict__ Qg, const bf16_t* __restrict__ Kg,
    const bf16_t* __restrict__ Vg, bf16_t* __restrict__ ctx) {
  __shared__ bf16_t ldsK[32 * 128];       // swizzled row-major K tile
  __shared__ bf16_t ldsVT[128 * 56];      // V^T tile, padded stride 56 (112B)
  __shared__ bf16_t ldsP[4][32 * 56];     // per-wave P, padded stride 56

  const int tid  = threadIdx.x;
  const int lane = tid & 63;
  const int w    = tid >> 6;
  const int g    = lane >> 4;
  const int l16  = lane & 15;
  const int bh   = blockIdx.y;
  const int q0   = blockIdx.x * 128;
  const int qw   = q0 + w * 32;

  const size_t bh_off = (size_t)bh * S_LEN * DHEAD;
  const bf16_t* Qb = Qg + bh_off;
  const bf16_t* Kb = Kg + bh_off;
  const bf16_t* Vb = Vg + bh_off;

  // Q fragments held in registers for the whole kernel
  bf16x8 qf[2][4];
#pragma unroll
  for (int i = 0; i < 2; ++i)
#pragma unroll
    for (int d0 = 0; d0 < 4; ++d0)
      qf[i][d0] = *(const bf16x8*)(Qb + (size_t)(qw + i * 16 + l16) * DHEAD + d0 * 32 + g * 8);

  f32x4 acc[2][8];
  float mrow[2][4], lrow[2][4];
#pragma unroll
  for (int i = 0; i < 2; ++i) {
#pragma unroll
    for (int df = 0; df < 8; ++df) acc[i][df] = (f32x4){0.f, 0.f, 0.f, 0.f};
#pragma unroll
    for (int r = 0; r < 4; ++r) { mrow[i][r] = -1e30f; lrow[i][r] = 0.f; }
  }

  const float sc = 0.08838834764831845f * 1.4426950408889634f;  // 1/sqrt(128) * log2(e)

  const int vr  = tid >> 3;         // 0..31   V row handled by this thread
  const int vc0 = (tid & 7) * 16;   // 0..112  V col base

  const int ntiles = (q0 + 128) >> 5;
  for (int t = 0; t < ntiles; ++t) {
    const int kt = t << 5;
    // ---- stage K tile, XOR-swizzled source so swizzled reads are conflict-free
#pragma unroll
    for (int it = 0; it < 2; ++it) {
      const int c    = w * 128 + it * 64 + lane;    // chunk 0..511
      const int krow = c >> 4;
      const int d16  = (c & 15) ^ (krow & 7);
      gload_lds16(Kb + (size_t)(kt + krow) * DHEAD + d16 * 8,
                  (char*)ldsK + (w * 128 + it * 64) * 16);
    }
    // ---- stage V transposed via registers
    {
      const bf16_t* gp = Vb + (size_t)(kt + vr) * DHEAD + vc0;
      const bf16x8 v0 = *(const bf16x8*)gp;
      const bf16x8 v1 = *(const bf16x8*)(gp + 8);
#pragma unroll
      for (int e = 0; e < 8; ++e) ldsVT[(vc0 + e) * 56 + vr] = v0[e];
#pragma unroll
      for (int e = 0; e < 8; ++e) ldsVT[(vc0 + 8 + e) * 56 + vr] = v1[e];
    }
    asm volatile("s_waitcnt vmcnt(0)" ::: "memory");
    __syncthreads();

    if (kt <= qw + 31) {   // causal early-skip per wave
      // ---- QK^T
      f32x4 sfr[2][2];
      sfr[0][0] = (f32x4){0.f,0.f,0.f,0.f}; sfr[0][1] = (f32x4){0.f,0.f,0.f,0.f};
      sfr[1][0] = (f32x4){0.f,0.f,0.f,0.f}; sfr[1][1] = (f32x4){0.f,0.f,0.f,0.f};
#pragma unroll
      for (int kf = 0; kf < 2; ++kf) {
        const int krow = kf * 16 + l16;
        const int swz  = (krow & 7) << 4;
#pragma unroll
        for (int d0 = 0; d0 < 4; ++d0) {
          const bf16x8 kfr = *(const bf16x8*)((const char*)ldsK + krow * 256 +
                                              ((d0 * 64 + g * 16) ^ swz));
          sfr[0][kf] = MFMA_BF16(qf[0][d0], kfr, sfr[0][kf]);
          sfr[1][kf] = MFMA_BF16(qf[1][d0], kfr, sfr[1][kf]);
        }
      }
      // ---- online softmax (exp2 domain)
#pragma unroll
      for (int i = 0; i < 2; ++i) {
#pragma unroll
        for (int r = 0; r < 4; ++r) {
          const int q = qw + i * 16 + g * 4 + r;
          float s0 = sfr[i][0][r] * sc;
          float s1 = sfr[i][1][r] * sc;
          if (kt + l16 > q)      s0 = -1e30f;
          if (kt + 16 + l16 > q) s1 = -1e30f;
          float tm = fmaxf(s0, s1);
          tm = fmaxf(tm, __shfl_xor(tm, 1));
          tm = fmaxf(tm, __shfl_xor(tm, 2));
          tm = fmaxf(tm, __shfl_xor(tm, 4));
          tm = fmaxf(tm, __shfl_xor(tm, 8));
          const float mold = mrow[i][r];
          const float mnew = fmaxf(mold, tm);
          const float corr = exp2f(mold - mnew);
          const float p0 = exp2f(s0 - mnew);
          const float p1 = exp2f(s1 - mnew);
          float rs = p0 + p1;
          rs += __shfl_xor(rs, 1);
          rs += __shfl_xor(rs, 2);
          rs += __shfl_xor(rs, 4);
          rs += __shfl_xor(rs, 8);
          mrow[i][r] = mnew;
          lrow[i][r] = lrow[i][r] * corr + rs;
#pragma unroll
          for (int df = 0; df < 8; ++df) acc[i][df][r] *= corr;
          const int prow = i * 16 + g * 4 + r;
          ldsP[w][prow * 56 + l16]      = (bf16_t)p0;
          ldsP[w][prow * 56 + 16 + l16] = (bf16_t)p1;
        }
      }
      asm volatile("s_waitcnt lgkmcnt(0)" ::: "memory");
      // ---- PV
      const bf16x8 pa0 = *(const bf16x8*)((const char*)&ldsP[w][0] + (size_t)(l16) * 112 + g * 16);
      const bf16x8 pa1 = *(const bf16x8*)((const char*)&ldsP[w][0] + (size_t)(16 + l16) * 112 + g * 16);
#pragma unroll
      for (int df = 0; df < 8; ++df) {
        const bf16x8 vb = *(const bf16x8*)((const char*)ldsVT + (size_t)(df * 16 + l16) * 112 + g * 16);
        acc[0][df] = MFMA_BF16(pa0, vb, acc[0][df]);
        acc[1][df] = MFMA_BF16(pa1, vb, acc[1][df]);
      }
    }
    __syncthreads();
  }

  // ---- epilogue: normalize and write ctx [B][S][H*D] bf16
  const int b = bh >> 4, h = bh & 15;
#pragma unroll
  for (int i = 0; i < 2; ++i) {
#pragma unroll
    for (int r = 0; r < 4; ++r) {
      const int q     = qw + i * 16 + g * 4 + r;
      const float inv = 1.0f / lrow[i][r];
      const size_t base = ((size_t)(b * S_LEN + q)) * DMODEL + h * DHEAD;
#pragma unroll
      for (int df = 0; df < 8; ++df)
        ctx[base + df * 16 + l16] = (bf16_t)(acc[i][df][r] * inv);
    }
  }
}

// ------------------------------------------------------------------------- launch
extern "C" void kernel_launch(void* const* d_in, const int* in_sizes, int n_in,
                              void* d_out, int out_size, void* d_ws, size_t ws_size,
                              hipStream_t stream) {
  const float* x  = (const float*)d_in[0];
  const float* Wq = (const float*)d_in[1];
  const float* bq = (const float*)d_in[2];
  const float* Wk = (const float*)d_in[3];
  const float* bk = (const float*)d_in[4];
  const float* Wv = (const float*)d_in[5];
  const float* bv = (const float*)d_in[6];
  const float* Wo = (const float*)d_in[7];
  const float* bo = (const float*)d_in[8];

  char* ws = (char*)d_ws;
  const size_t MB = 1ull << 20;
  bf16_t* Xb  = (bf16_t*)(ws + 0);
  bf16_t* WqT = (bf16_t*)(ws + 16 * MB);
  bf16_t* WkT = (bf16_t*)(ws + 24 * MB);
  bf16_t* WvT = (bf16_t*)(ws + 32 * MB);
  bf16_t* WoT = (bf16_t*)(ws + 40 * MB);
  bf16_t* Qg  = (bf16_t*)(ws + 48 * MB);
  bf16_t* Kg  = (bf16_t*)(ws + 64 * MB);
  bf16_t* Vg  = (bf16_t*)(ws + 80 * MB);
  bf16_t* Ctx = (bf16_t*)(ws + 96 * MB);
  if (ws_size < 112 * MB) return;   // insufficient workspace -> fail loudly in validation

  cast_kernel<<<dim3(MROWS * DMODEL / (256 * 8)), 256, 0, stream>>>(x, Xb);
  transpose_cast<<<dim3(32, 32, 4), 256, 0, stream>>>(Wq, Wk, Wv, Wo, WqT, WkT, WvT, WoT);
  gemm_qkv<<<dim3(DMODEL / 128, MROWS / 128, 3), 256, 0, stream>>>(
      Xb, WqT, WkT, WvT, bq, bk, bv, Qg, Kg, Vg);
  attn_kernel<<<dim3(S_LEN / 128, NBATCH * NHEADS), 256, 0, stream>>>(Qg, Kg, Vg, Ctx);
  gemm_out<<<dim3(DMODEL / 128, MROWS / 128), 256, 0, stream>>>(Ctx, WoT, bo, (float*)d_out);
}

// Round 3
// 265.976 us; speedup vs baseline: 1.6546x; 1.6546x over previous
//
#include <hip/hip_runtime.h>
#include <hip/hip_bf16.h>
#include <stdint.h>

#define S_LEN  2048
#define DMODEL 2048
#define NHEADS 16
#define DHEAD  128
#define NBATCH 2
#define MROWS  (NBATCH * S_LEN)   // 4096

typedef __bf16 bf16_t;
typedef __bf16 bf16x8 __attribute__((ext_vector_type(8)));
typedef float  f32x4  __attribute__((ext_vector_type(4)));
typedef float  f32x16 __attribute__((ext_vector_type(16)));

#define MFMA_BF16(A, B, C) __builtin_amdgcn_mfma_f32_16x16x32_bf16((A), (B), (C), 0, 0, 0)
#define MFMA32(A, B, C)    __builtin_amdgcn_mfma_f32_32x32x16_bf16((A), (B), (C), 0, 0, 0)

__device__ __forceinline__ void gload_lds16(const void* g, void* l) {
  __builtin_amdgcn_global_load_lds(
      (__attribute__((address_space(1))) uint32_t*)(uintptr_t)g,
      (__attribute__((address_space(3))) uint32_t*)l,
      16, 0, 0);
}

// pack two f32 -> one u32 of two bf16 (RNE via compiler casts)
__device__ __forceinline__ unsigned pk2(float lo, float hi) {
  const unsigned short a = __builtin_bit_cast(unsigned short, (bf16_t)lo);
  const unsigned short b = __builtin_bit_cast(unsigned short, (bf16_t)hi);
  return (unsigned)a | ((unsigned)b << 16);
}

// ---------------------------------------------------------------- cast x -> bf16
__global__ __launch_bounds__(256) void cast_kernel(const float* __restrict__ X,
                                                   bf16_t* __restrict__ Xb) {
  const int i = blockIdx.x * 256 + threadIdx.x;
  const f32x4 a = ((const f32x4*)X)[2 * i];
  const f32x4 b = ((const f32x4*)X)[2 * i + 1];
  bf16x8 o;
#pragma unroll
  for (int j = 0; j < 4; ++j) { o[j] = (bf16_t)a[j]; o[j + 4] = (bf16_t)b[j]; }
  ((bf16x8*)Xb)[i] = o;
}

// ---------------------------------------------------- W [K][N] f32 -> Wt [N][K] bf16
__global__ __launch_bounds__(256) void transpose_cast(
    const float* __restrict__ W0, const float* __restrict__ W1,
    const float* __restrict__ W2, const float* __restrict__ W3,
    bf16_t* __restrict__ T0, bf16_t* __restrict__ T1,
    bf16_t* __restrict__ T2, bf16_t* __restrict__ T3) {
  const float* W; bf16_t* T;
  switch (blockIdx.z) {
    case 0:  W = W0; T = T0; break;
    case 1:  W = W1; T = T1; break;
    case 2:  W = W2; T = T2; break;
    default: W = W3; T = T3; break;
  }
  __shared__ float tile[64][65];
  const int r0 = blockIdx.y * 64;
  const int c0 = blockIdx.x * 64;
  const int tx = threadIdx.x & 63;
  const int ty = threadIdx.x >> 6;
#pragma unroll
  for (int i = 0; i < 16; ++i) {
    const int r = ty + i * 4;
    tile[r][tx] = W[(size_t)(r0 + r) * DMODEL + c0 + tx];
  }
  __syncthreads();
#pragma unroll
  for (int i = 0; i < 16; ++i) {
    const int r = ty + i * 4;
    T[(size_t)(c0 + r) * DMODEL + r0 + tx] = (bf16_t)tile[tx][r];
  }
}

// -------------------------------------- V [bh][2048][128] -> VT [bh][128][2048] bf16
__global__ __launch_bounds__(256) void transpose_v(const bf16_t* __restrict__ V,
                                                   bf16_t* __restrict__ VT) {
  __shared__ bf16_t tile[64 * 64];   // XOR-swizzled 64x64 tile
  const int bh = blockIdx.z;
  const int s0 = blockIdx.x * 64;
  const int d0 = blockIdx.y * 64;
  const bf16_t* src = V + ((size_t)bh * S_LEN + s0) * DHEAD + d0;
#pragma unroll
  for (int i = 0; i < 2; ++i) {
    const int v = threadIdx.x + i * 256;     // 0..511
    const int r = v >> 3, ch = v & 7;
    *(bf16x8*)&tile[r * 64 + ((ch ^ ((r >> 3) & 7)) << 3)] =
        *(const bf16x8*)(src + (size_t)r * DHEAD + ch * 8);
  }
  __syncthreads();
  bf16_t* dst = VT + ((size_t)bh * DHEAD + d0) * S_LEN + s0;
#pragma unroll
  for (int i = 0; i < 2; ++i) {
    const int v = threadIdx.x + i * 256;
    const int d = v >> 3, j = v & 7;         // out row d, col block j
    bf16x8 o;
#pragma unroll
    for (int e = 0; e < 8; ++e) {
      const int row = j * 8 + e;
      o[e] = tile[row * 64 + (((d >> 3) ^ j) << 3) + (d & 7)];
    }
    *(bf16x8*)(dst + (size_t)d * S_LEN + j * 8) = o;
  }
}

// ------------------------------------------------------------------ m97-style GEMM
template <int MODE>
__device__ __forceinline__ void gemm_body(const bf16_t* __restrict__ A,
                                          const bf16_t* __restrict__ Bt,
                                          const float* __restrict__ bias,
                                          void* __restrict__ out) {
  __shared__ bf16_t lds[128 * 32 * 2];   // A tile | B tile, 8KB each
  const int tid  = threadIdx.x;
  const int lane = tid & 63;
  const int w    = tid >> 6;
  const int g    = lane >> 4;
  const int l16  = lane & 15;
  const int m0   = blockIdx.y * 128;
  const int n0   = blockIdx.x * 128;
  const int wm   = w >> 1, wn = w & 1;

  f32x4 acc[4][4];
#pragma unroll
  for (int i = 0; i < 4; ++i)
#pragma unroll
    for (int j = 0; j < 4; ++j) acc[i][j] = (f32x4){0.f, 0.f, 0.f, 0.f};

  const bf16_t* src   = (w < 2) ? A : Bt;
  const int rowbase   = (w < 2) ? m0 : n0;
  char* ldsst         = (char*)lds + (w >= 2 ? 8192 : 0);
  const char* lA      = (const char*)lds;
  const char* lB      = (const char*)lds + 8192;

  for (int kt = 0; kt < DMODEL; kt += 32) {
#pragma unroll
    for (int it = 0; it < 4; ++it) {
      const int c   = (w & 1) * 256 + it * 64 + lane;
      const int row = c >> 2;
      const int q4  = (c & 3) ^ (row & 3);
      gload_lds16(src + (size_t)(rowbase + row) * DMODEL + kt + q4 * 8,
                  ldsst + ((w & 1) * 256 + it * 64) * 16);
    }
    asm volatile("s_waitcnt vmcnt(0)" ::: "memory");
    __syncthreads();

    bf16x8 af[4], bfr[4];
#pragma unroll
    for (int i = 0; i < 4; ++i) {
      const int row = wm * 64 + i * 16 + l16;
      af[i] = *(const bf16x8*)(lA + row * 64 + ((g * 16) ^ ((row & 3) << 4)));
    }
#pragma unroll
    for (int j = 0; j < 4; ++j) {
      const int row = wn * 64 + j * 16 + l16;
      bfr[j] = *(const bf16x8*)(lB + row * 64 + ((g * 16) ^ ((row & 3) << 4)));
    }
#pragma unroll
    for (int i = 0; i < 4; ++i)
#pragma unroll
      for (int j = 0; j < 4; ++j)
        acc[i][j] = MFMA_BF16(af[i], bfr[j], acc[i][j]);
    __syncthreads();
  }

#pragma unroll
  for (int i = 0; i < 4; ++i) {
#pragma unroll
    for (int j = 0; j < 4; ++j) {
      const int n    = n0 + wn * 64 + j * 16 + l16;
      const float bb = bias[n];
#pragma unroll
      for (int r = 0; r < 4; ++r) {
        const int m   = m0 + wm * 64 + i * 16 + g * 4 + r;
        const float v = acc[i][j][r] + bb;
        if (MODE == 0) {
          const int b = m >> 11, s = m & (S_LEN - 1);
          const int h = n >> 7,  d = n & (DHEAD - 1);
          ((bf16_t*)out)[((size_t)(b * NHEADS + h) * S_LEN + s) * DHEAD + d] = (bf16_t)v;
        } else {
          ((float*)out)[(size_t)m * DMODEL + n] = v;
        }
      }
    }
  }
}

__global__ __launch_bounds__(256, 2) void gemm_qkv(
    const bf16_t* __restrict__ Xb,
    const bf16_t* __restrict__ WqT, const bf16_t* __restrict__ WkT,
    const bf16_t* __restrict__ WvT,
    const float* __restrict__ bq, const float* __restrict__ bk,
    const float* __restrict__ bv,
    bf16_t* __restrict__ Qg, bf16_t* __restrict__ Kg, bf16_t* __restrict__ Vg) {
  const bf16_t* Bt; const float* bias; bf16_t* out;
  if (blockIdx.z == 0)      { Bt = WqT; bias = bq; out = Qg; }
  else if (blockIdx.z == 1) { Bt = WkT; bias = bk; out = Kg; }
  else                      { Bt = WvT; bias = bv; out = Vg; }
  gemm_body<0>(Xb, Bt, bias, out);
}

__global__ __launch_bounds__(256, 2) void gemm_out(
    const bf16_t* __restrict__ Ctx, const bf16_t* __restrict__ WoT,
    const float* __restrict__ bo, float* __restrict__ out) {
  gemm_body<1>(Ctx, WoT, bo, out);
}

// --------------------------------------------------------------- flash attention
// 4 waves x 32 q-rows = 128 q/block, KVBLK=64, swapped QK^T, in-register softmax.
#define KLDS_BYTES (64 * 272)            // 17408
#define VLDS_BYTES (128 * 144)           // 18432
#define BUF_BYTES  (KLDS_BYTES + VLDS_BYTES)

__global__ __launch_bounds__(256, 2) void attn_kernel(
    const bf16_t* __restrict__ Qg, const bf16_t* __restrict__ Kg,
    const bf16_t* __restrict__ VTg, bf16_t* __restrict__ ctx) {
  __shared__ __align__(16) char ldsbuf[2][BUF_BYTES];
  __shared__ float lbuf[4][32];

  const int tid  = threadIdx.x;
  const int lane = tid & 63;
  const int w    = tid >> 6;
  const int l31  = lane & 31;
  const int hi   = lane >> 5;

  const int id   = blockIdx.x;                  // 512 blocks
  const int bh   = id & 31;
  const int jraw = id >> 5;
  const int j    = (jraw < 8) ? jraw : 23 - jraw;   // pair (j,15-j) co-resident
  const int q0   = j * 128;
  const int qw   = q0 + w * 32;
  const int tq   = (qw + 31) >> 6;              // diagonal tile index for this wave
  const int NT   = (q0 + 128) >> 6;             // tiles this block processes

  const size_t bho = (size_t)bh * S_LEN * DHEAD;
  const bf16_t* Qb  = Qg + bho;
  const bf16_t* Kb  = Kg + bho;
  const bf16_t* VTb = VTg + bho;                // [128][2048]

  // Q fragments: lane holds Q[qw+l31][16s+8hi .. +8]
  bf16x8 qreg[8];
#pragma unroll
  for (int s = 0; s < 8; ++s)
    qreg[s] = *(const bf16x8*)(Qb + (size_t)(qw + l31) * DHEAD + s * 16 + hi * 8);

  f32x16 oacc[4];
#pragma unroll
  for (int d0 = 0; d0 < 4; ++d0)
#pragma unroll
    for (int e = 0; e < 16; ++e) oacc[d0][e] = 0.f;

  float m = -1e30f, lsum = 0.f;
  const float sc2 = 0.12751751135f;             // log2(e)/sqrt(128)

  bf16x8 kst[4], vst[4];
  // ---- prologue: stage tile 0
#pragma unroll
  for (int i = 0; i < 4; ++i) {
    const int c = tid + i * 256;
    kst[i] = *(const bf16x8*)(Kb + (size_t)(c >> 4) * DHEAD + (c & 15) * 8);
    vst[i] = *(const bf16x8*)(VTb + (size_t)(c >> 3) * S_LEN + (c & 7) * 8);
  }
#pragma unroll
  for (int i = 0; i < 4; ++i) {
    const int c  = tid + i * 256;
    const int kr = c >> 4, kc = c & 15;
    *(bf16x8*)(ldsbuf[0] + kr * 272 + ((kc ^ ((kr >> 3) & 3)) << 4)) = kst[i];
    const int vr = c >> 3, vc = c & 7;
    *(bf16x8*)(ldsbuf[0] + KLDS_BYTES + vr * 144 + ((vc ^ ((vr >> 3) & 3)) << 4)) = vst[i];
  }
  __syncthreads();

  for (int t = 0; t < NT; ++t) {
    const int kt = t << 6;
    const char* bK = ldsbuf[t & 1];
    const char* bV = bK + KLDS_BYTES;
    const bool hn = (t + 1 < NT);
    if (hn) {   // issue next-tile loads early (latency hides under compute)
#pragma unroll
      for (int i = 0; i < 4; ++i) {
        const int c = tid + i * 256;
        kst[i] = *(const bf16x8*)(Kb + (size_t)(kt + 64 + (c >> 4)) * DHEAD + (c & 15) * 8);
        vst[i] = *(const bf16x8*)(VTb + (size_t)(c >> 3) * S_LEN + kt + 64 + (c & 7) * 8);
      }
    }

    if (t <= tq) {
      // ---- swapped QK^T: D[kv][q], lane column q = l31
      f32x16 stt[2];
#pragma unroll
      for (int kh = 0; kh < 2; ++kh)
#pragma unroll
        for (int e = 0; e < 16; ++e) stt[kh][e] = 0.f;
#pragma unroll
      for (int kh = 0; kh < 2; ++kh) {
        const int row = kh * 32 + l31;
        const char* rb = bK + row * 272;
        const int swz = ((row >> 3) & 3) << 4;
#pragma unroll
        for (int s = 0; s < 8; ++s) {
          const bf16x8 kf = *(const bf16x8*)(rb + ((((s << 1) | hi) << 4) ^ swz));
          stt[kh] = MFMA32(kf, qreg[s], stt[kh]);
        }
      }
      // ---- causal mask (diagonal tile only)
      if (t == tq) {
        const int qg = qw + l31;
#pragma unroll
        for (int kh = 0; kh < 2; ++kh)
#pragma unroll
          for (int r = 0; r < 16; ++r) {
            const int kv = kt + kh * 32 + (r & 3) + 8 * (r >> 2) + 4 * hi;
            stt[kh][r] = (kv > qg) ? -1e30f : stt[kh][r];
          }
      }
      // ---- row max (in-lane + partner via shfl_xor 32)
      float pm = stt[0][0];
#pragma unroll
      for (int kh = 0; kh < 2; ++kh)
#pragma unroll
        for (int r = 0; r < 16; ++r)
          if (kh | r) pm = fmaxf(pm, stt[kh][r]);
      pm = fmaxf(pm, __shfl_xor(pm, 32));
      const float pmax = pm * sc2;
      // ---- defer-max rescale (T13, THR=8)
      if (!__all(pmax <= m + 8.f)) {
        const float mn   = fmaxf(m, pmax);
        const float corr = __builtin_amdgcn_exp2f(m - mn);
        m = mn;
        lsum *= corr;
        if (!hi) lbuf[w][l31] = corr;
#pragma unroll
        for (int r = 0; r < 16; ++r) {
          const float cr = lbuf[w][(r & 3) + 8 * (r >> 2) + 4 * hi];
#pragma unroll
          for (int d0 = 0; d0 < 4; ++d0) oacc[d0][r] *= cr;
        }
      }
      // ---- p = exp2(s*sc2 - m), row sum
      float rs = 0.f;
#pragma unroll
      for (int kh = 0; kh < 2; ++kh)
#pragma unroll
        for (int r = 0; r < 16; ++r) {
          const float p = __builtin_amdgcn_exp2f(__builtin_fmaf(stt[kh][r], sc2, -m));
          stt[kh][r] = p;
          rs += p;
        }
      rs += __shfl_xor(rs, 32);
      lsum += rs;
      // ---- pack P to bf16 A-fragments: manual pack + shfl_xor(32) + hi-select
      unsigned pw_[2][8];
#pragma unroll
      for (int kh = 0; kh < 2; ++kh)
#pragma unroll
        for (int jj = 0; jj < 8; ++jj)
          pw_[kh][jj] = pk2(stt[kh][2 * jj], stt[kh][2 * jj + 1]);
      bf16x8 pa[4];
#pragma unroll
      for (int kh = 0; kh < 2; ++kh)
#pragma unroll
        for (int c2 = 0; c2 < 2; ++c2) {
          const unsigned o0 = pw_[kh][4 * c2 + 0], o1 = pw_[kh][4 * c2 + 1];
          const unsigned o2 = pw_[kh][4 * c2 + 2], o3 = pw_[kh][4 * c2 + 3];
          const unsigned p0 = (unsigned)__shfl_xor((int)o0, 32);
          const unsigned p1 = (unsigned)__shfl_xor((int)o1, 32);
          const unsigned p2 = (unsigned)__shfl_xor((int)o2, 32);
          const unsigned p3 = (unsigned)__shfl_xor((int)o3, 32);
          union { unsigned u[4]; bf16x8 v; } uu;
          uu.u[0] = hi ? p2 : o0;
          uu.u[1] = hi ? p3 : o1;
          uu.u[2] = hi ? o2 : p0;
          uu.u[3] = hi ? o3 : p1;
          pa[2 * kh + c2] = uu.v;
        }
      // ---- PV: D[q][d] += P * V
#pragma unroll
      for (int d0 = 0; d0 < 4; ++d0) {
        const int row = d0 * 32 + l31;
        const char* rb = bV + row * 144;
        const int swz = ((row >> 3) & 3) << 4;
#pragma unroll
        for (int ks = 0; ks < 4; ++ks) {
          const bf16x8 vb = *(const bf16x8*)(rb + ((((ks << 1) | hi) << 4) ^ swz));
          oacc[d0] = MFMA32(pa[ks], vb, oacc[d0]);
        }
      }
    }
    __syncthreads();   // A: all reads of buf[(t+1)&1] (from iter t-1) complete
    if (hn) {
      char* nB = ldsbuf[(t + 1) & 1];
#pragma unroll
      for (int i = 0; i < 4; ++i) {
        const int c  = tid + i * 256;
        const int kr = c >> 4, kc = c & 15;
        *(bf16x8*)(nB + kr * 272 + ((kc ^ ((kr >> 3) & 3)) << 4)) = kst[i];
        const int vr = c >> 3, vc = c & 7;
        *(bf16x8*)(nB + KLDS_BYTES + vr * 144 + ((vc ^ ((vr >> 3) & 3)) << 4)) = vst[i];
      }
    }
    __syncthreads();   // B: staged tile visible
  }

  // ---- epilogue: normalize, write ctx [B][S][H*D] bf16
  if (!hi) lbuf[w][l31] = 1.0f / lsum;
  const int b = bh >> 4, h = bh & 15;
#pragma unroll
  for (int r = 0; r < 16; ++r) {
    const int cro = (r & 3) + 8 * (r >> 2) + 4 * hi;
    const float li = lbuf[w][cro];
    const size_t base = ((size_t)(b * S_LEN + qw + cro)) * DMODEL + h * DHEAD;
#pragma unroll
    for (int d0 = 0; d0 < 4; ++d0)
      ctx[base + d0 * 32 + l31] = (bf16_t)(oacc[d0][r] * li);
  }
}

// ------------------------------------------------------------------------- launch
extern "C" void kernel_launch(void* const* d_in, const int* in_sizes, int n_in,
                              void* d_out, int out_size, void* d_ws, size_t ws_size,
                              hipStream_t stream) {
  const float* x  = (const float*)d_in[0];
  const float* Wq = (const float*)d_in[1];
  const float* bq = (const float*)d_in[2];
  const float* Wk = (const float*)d_in[3];
  const float* bk = (const float*)d_in[4];
  const float* Wv = (const float*)d_in[5];
  const float* bv = (const float*)d_in[6];
  const float* Wo = (const float*)d_in[7];
  const float* bo = (const float*)d_in[8];

  char* ws = (char*)d_ws;
  const size_t MB = 1ull << 20;
  bf16_t* Xb  = (bf16_t*)(ws + 0);          // x bf16 (dead after gemm_qkv)
  bf16_t* VTg = (bf16_t*)(ws + 0);          // V^T reuses Xb's slot
  bf16_t* WqT = (bf16_t*)(ws + 16 * MB);
  bf16_t* WkT = (bf16_t*)(ws + 24 * MB);
  bf16_t* WvT = (bf16_t*)(ws + 32 * MB);
  bf16_t* WoT = (bf16_t*)(ws + 40 * MB);
  bf16_t* Qg  = (bf16_t*)(ws + 48 * MB);
  bf16_t* Kg  = (bf16_t*)(ws + 64 * MB);
  bf16_t* Vg  = (bf16_t*)(ws + 80 * MB);
  bf16_t* Ctx = (bf16_t*)(ws + 96 * MB);
  if (ws_size < 112 * MB) return;

  cast_kernel<<<dim3(MROWS * DMODEL / (256 * 8)), 256, 0, stream>>>(x, Xb);
  transpose_cast<<<dim3(32, 32, 4), 256, 0, stream>>>(Wq, Wk, Wv, Wo, WqT, WkT, WvT, WoT);
  gemm_qkv<<<dim3(DMODEL / 128, MROWS / 128, 3), 256, 0, stream>>>(
      Xb, WqT, WkT, WvT, bq, bk, bv, Qg, Kg, Vg);
  transpose_v<<<dim3(32, 2, 32), 256, 0, stream>>>(Vg, VTg);
  attn_kernel<<<dim3(512), 256, 0, stream>>>(Qg, Kg, VTg, Ctx);
  gemm_out<<<dim3(DMODEL / 128, MROWS / 128), 256, 0, stream>>>(Ctx, WoT, bo, (float*)d_out);
}

// Round 4
// 235.116 us; speedup vs baseline: 1.8718x; 1.1313x over previous
//
#include <hip/hip_runtime.h>
#include <hip/hip_bf16.h>
#include <stdint.h>

#define S_LEN  2048
#define DMODEL 2048
#define NHEADS 16
#define DHEAD  128
#define NBATCH 2
#define MROWS  (NBATCH * S_LEN)   // 4096

typedef __bf16 bf16_t;
typedef __bf16 bf16x8 __attribute__((ext_vector_type(8)));
typedef float  f32x4  __attribute__((ext_vector_type(4)));
typedef float  f32x16 __attribute__((ext_vector_type(16)));

#define MFMA_BF16(A, B, C) __builtin_amdgcn_mfma_f32_16x16x32_bf16((A), (B), (C), 0, 0, 0)
#define MFMA32(A, B, C)    __builtin_amdgcn_mfma_f32_32x32x16_bf16((A), (B), (C), 0, 0, 0)

__device__ __forceinline__ void gload_lds16(const void* g, void* l) {
  __builtin_amdgcn_global_load_lds(
      (__attribute__((address_space(1))) uint32_t*)(uintptr_t)g,
      (__attribute__((address_space(3))) uint32_t*)l,
      16, 0, 0);
}

// pack two f32 -> one u32 of two bf16 (RNE via compiler casts)
__device__ __forceinline__ unsigned pk2(float lo, float hi) {
  const unsigned short a = __builtin_bit_cast(unsigned short, (bf16_t)lo);
  const unsigned short b = __builtin_bit_cast(unsigned short, (bf16_t)hi);
  return (unsigned)a | ((unsigned)b << 16);
}

// ---------------------------------------------------------------- cast x -> bf16
__global__ __launch_bounds__(256) void cast_kernel(const float* __restrict__ X,
                                                   bf16_t* __restrict__ Xb) {
  const int i = blockIdx.x * 256 + threadIdx.x;
  const f32x4 a = ((const f32x4*)X)[2 * i];
  const f32x4 b = ((const f32x4*)X)[2 * i + 1];
  bf16x8 o;
#pragma unroll
  for (int j = 0; j < 4; ++j) { o[j] = (bf16_t)a[j]; o[j + 4] = (bf16_t)b[j]; }
  ((bf16x8*)Xb)[i] = o;
}

// ---------------------------------------------------- W [K][N] f32 -> Wt [N][K] bf16
__global__ __launch_bounds__(256) void transpose_cast(
    const float* __restrict__ W0, const float* __restrict__ W1,
    const float* __restrict__ W2, const float* __restrict__ W3,
    bf16_t* __restrict__ T0, bf16_t* __restrict__ T1,
    bf16_t* __restrict__ T2, bf16_t* __restrict__ T3) {
  const float* W; bf16_t* T;
  switch (blockIdx.z) {
    case 0:  W = W0; T = T0; break;
    case 1:  W = W1; T = T1; break;
    case 2:  W = W2; T = T2; break;
    default: W = W3; T = T3; break;
  }
  __shared__ float tile[64][65];
  const int r0 = blockIdx.y * 64;
  const int c0 = blockIdx.x * 64;
  const int tx = threadIdx.x & 63;
  const int ty = threadIdx.x >> 6;
#pragma unroll
  for (int i = 0; i < 16; ++i) {
    const int r = ty + i * 4;
    tile[r][tx] = W[(size_t)(r0 + r) * DMODEL + c0 + tx];
  }
  __syncthreads();
#pragma unroll
  for (int i = 0; i < 16; ++i) {
    const int r = ty + i * 4;
    T[(size_t)(c0 + r) * DMODEL + r0 + tx] = (bf16_t)tile[tx][r];
  }
}

// -------------------------------------- V [bh][2048][128] -> VT [bh][128][2048] bf16
__global__ __launch_bounds__(256) void transpose_v(const bf16_t* __restrict__ V,
                                                   bf16_t* __restrict__ VT) {
  __shared__ bf16_t tile[64 * 64];   // XOR-swizzled 64x64 tile
  const int bh = blockIdx.z;
  const int s0 = blockIdx.x * 64;
  const int d0 = blockIdx.y * 64;
  const bf16_t* src = V + ((size_t)bh * S_LEN + s0) * DHEAD + d0;
#pragma unroll
  for (int i = 0; i < 2; ++i) {
    const int v = threadIdx.x + i * 256;     // 0..511
    const int r = v >> 3, ch = v & 7;
    *(bf16x8*)&tile[r * 64 + ((ch ^ ((r >> 3) & 7)) << 3)] =
        *(const bf16x8*)(src + (size_t)r * DHEAD + ch * 8);
  }
  __syncthreads();
  bf16_t* dst = VT + ((size_t)bh * DHEAD + d0) * S_LEN + s0;
#pragma unroll
  for (int i = 0; i < 2; ++i) {
    const int v = threadIdx.x + i * 256;
    const int d = v >> 3, j = v & 7;         // out row d, col block j
    bf16x8 o;
#pragma unroll
    for (int e = 0; e < 8; ++e) {
      const int row = j * 8 + e;
      o[e] = tile[row * 64 + (((d >> 3) ^ j) << 3) + (d & 7)];
    }
    *(bf16x8*)(dst + (size_t)d * S_LEN + j * 8) = o;
  }
}

// ------------------------------------------- 8-phase-style GEMM: BM=128 BN=256 BK=64
// A [M][2048] bf16 row-major, Bt [N][2048] bf16; 512 thr = 8 waves (2M x 4N),
// per-wave 64x64 out. LDS/buffer: A[128][64] @0, B rows 0-127 @16K, 128-255 @32K.
// Rows 128B; 16B-chunk swizzle ch ^= (row&7) (staged via inverse-swizzled source).
// Stage units: (tile, r): r0=A, r1=B0, r2=B1; lead 3 units; vmcnt(2) once/tile.
template <int MODE>
__device__ __forceinline__ void gemm8_body(const bf16_t* __restrict__ A,
                                           const bf16_t* __restrict__ Bt,
                                           const float* __restrict__ bias,
                                           void* __restrict__ out) {
  __shared__ __align__(16) char lds8[2 * 49152];   // 96 KB
  const int tid  = threadIdx.x;
  const int lane = tid & 63;
  const int w    = tid >> 6;
  const int g    = lane >> 4;
  const int l16  = lane & 15;
  const int wm   = w >> 2;       // 0..1
  const int wn   = w & 3;        // 0..3
  const int m0   = blockIdx.y * 128;
  const int n0   = blockIdx.x * 256;

  f32x4 acc[4][4];
#pragma unroll
  for (int i = 0; i < 4; ++i)
#pragma unroll
    for (int j = 0; j < 4; ++j) acc[i][j] = (f32x4){0.f, 0.f, 0.f, 0.f};

  const int st_r0 = tid >> 3;    // staging row (jj=0), +64 for jj=1
  const int st_ch = tid & 7;     // staging 16B-chunk slot

  auto stage = [&](int tile, int r) {
    if (tile >= DMODEL / 64) return;
    const int kt = tile << 6;
    char* db = lds8 + (tile & 1) * 49152 + r * 16384 + w * 1024;
    const bf16_t* sb = (r == 0) ? (A + (size_t)m0 * DMODEL + kt)
                                : (Bt + (size_t)(n0 + ((r - 1) << 7)) * DMODEL + kt);
#pragma unroll
    for (int jj = 0; jj < 2; ++jj) {
      const int row = jj * 64 + st_r0;
      gload_lds16(sb + (size_t)row * DMODEL + ((st_ch ^ (row & 7)) << 3),
                  db + jj * 8192);
    }
  };

  // prologue: tile0 fully + tile1 A; leave tile1-A's 2 loads outstanding
  stage(0, 0); stage(0, 1); stage(0, 2); stage(1, 0);
  asm volatile("s_waitcnt vmcnt(2)" ::: "memory");
  __builtin_amdgcn_s_barrier();

#pragma unroll 2
  for (int t = 0; t < DMODEL / 64; ++t) {
    const char* cb = lds8 + (t & 1) * 49152;
    bf16x8 af[4][2], b0[2][2], b1[2][2];
    // ---- phase 0: read A frags (8) + B n0-1 frags (4); stage (t+1,B0),(t+1,B1)
#pragma unroll
    for (int i = 0; i < 4; ++i) {
      const int row = wm * 64 + i * 16 + l16;
      const char* rp = cb + row * 128;
#pragma unroll
      for (int ks = 0; ks < 2; ++ks)
        af[i][ks] = *(const bf16x8*)(rp + ((((ks << 2) | g) ^ (row & 7)) << 4));
    }
#pragma unroll
    for (int j = 0; j < 2; ++j) {
      const int row = (wn & 1) * 64 + j * 16 + l16;
      const char* rp = cb + 16384 + (wn >> 1) * 16384 + row * 128;
#pragma unroll
      for (int ks = 0; ks < 2; ++ks)
        b0[j][ks] = *(const bf16x8*)(rp + ((((ks << 2) | g) ^ (row & 7)) << 4));
    }
    stage(t + 1, 1); stage(t + 1, 2);
    __builtin_amdgcn_s_barrier();
    asm volatile("s_waitcnt lgkmcnt(0)" ::: "memory");
    __builtin_amdgcn_s_setprio(1);
#pragma unroll
    for (int i = 0; i < 4; ++i)
#pragma unroll
      for (int j = 0; j < 2; ++j) {
        acc[i][j] = MFMA_BF16(af[i][0], b0[j][0], acc[i][j]);
        acc[i][j] = MFMA_BF16(af[i][1], b0[j][1], acc[i][j]);
      }
    __builtin_amdgcn_s_setprio(0);
    __builtin_amdgcn_s_barrier();
    // ---- phase 1: read B n2-3 frags (4); stage (t+2,A)
#pragma unroll
    for (int j = 0; j < 2; ++j) {
      const int row = (wn & 1) * 64 + (j + 2) * 16 + l16;
      const char* rp = cb + 16384 + (wn >> 1) * 16384 + row * 128;
#pragma unroll
      for (int ks = 0; ks < 2; ++ks)
        b1[j][ks] = *(const bf16x8*)(rp + ((((ks << 2) | g) ^ (row & 7)) << 4));
    }
    stage(t + 2, 0);
    __builtin_amdgcn_s_barrier();
    asm volatile("s_waitcnt lgkmcnt(0)" ::: "memory");
    __builtin_amdgcn_s_setprio(1);
#pragma unroll
    for (int i = 0; i < 4; ++i)
#pragma unroll
      for (int j = 0; j < 2; ++j) {
        acc[i][j + 2] = MFMA_BF16(af[i][0], b1[j][0], acc[i][j + 2]);
        acc[i][j + 2] = MFMA_BF16(af[i][1], b1[j][1], acc[i][j + 2]);
      }
    __builtin_amdgcn_s_setprio(0);
    if (t < DMODEL / 64 - 2) asm volatile("s_waitcnt vmcnt(2)" ::: "memory");
    else                     asm volatile("s_waitcnt vmcnt(0)" ::: "memory");
    __builtin_amdgcn_s_barrier();
  }

#pragma unroll
  for (int i = 0; i < 4; ++i) {
#pragma unroll
    for (int j = 0; j < 4; ++j) {
      const int n    = n0 + wn * 64 + j * 16 + l16;
      const float bb = bias[n];
#pragma unroll
      for (int r = 0; r < 4; ++r) {
        const int m   = m0 + wm * 64 + i * 16 + g * 4 + r;
        const float v = acc[i][j][r] + bb;
        if (MODE == 0) {
          const int b = m >> 11, s = m & (S_LEN - 1);
          const int h = n >> 7,  d = n & (DHEAD - 1);
          ((bf16_t*)out)[((size_t)(b * NHEADS + h) * S_LEN + s) * DHEAD + d] = (bf16_t)v;
        } else {
          ((float*)out)[(size_t)m * DMODEL + n] = v;
        }
      }
    }
  }
}

__global__ __launch_bounds__(512, 2) void gemm_qkv(
    const bf16_t* __restrict__ Xb,
    const bf16_t* __restrict__ WqT, const bf16_t* __restrict__ WkT,
    const bf16_t* __restrict__ WvT,
    const float* __restrict__ bq, const float* __restrict__ bk,
    const float* __restrict__ bv,
    bf16_t* __restrict__ Qg, bf16_t* __restrict__ Kg, bf16_t* __restrict__ Vg) {
  const bf16_t* Bt; const float* bias; bf16_t* out;
  if (blockIdx.z == 0)      { Bt = WqT; bias = bq; out = Qg; }
  else if (blockIdx.z == 1) { Bt = WkT; bias = bk; out = Kg; }
  else                      { Bt = WvT; bias = bv; out = Vg; }
  gemm8_body<0>(Xb, Bt, bias, out);
}

__global__ __launch_bounds__(512, 2) void gemm_out(
    const bf16_t* __restrict__ Ctx, const bf16_t* __restrict__ WoT,
    const float* __restrict__ bo, float* __restrict__ out) {
  gemm8_body<1>(Ctx, WoT, bo, out);
}

// --------------------------------------------------------------- flash attention
// 4 waves x 32 q-rows = 128 q/block, KVBLK=64, swapped QK^T, in-register softmax.
#define KLDS_BYTES (64 * 272)            // 17408
#define VLDS_BYTES (128 * 144)           // 18432
#define BUF_BYTES  (KLDS_BYTES + VLDS_BYTES)

__global__ __launch_bounds__(256, 2) void attn_kernel(
    const bf16_t* __restrict__ Qg, const bf16_t* __restrict__ Kg,
    const bf16_t* __restrict__ VTg, bf16_t* __restrict__ ctx) {
  __shared__ __align__(16) char ldsbuf[2][BUF_BYTES];
  __shared__ float lbuf[4][32];

  const int tid  = threadIdx.x;
  const int lane = tid & 63;
  const int w    = tid >> 6;
  const int l31  = lane & 31;
  const int hi   = lane >> 5;

  const int id   = blockIdx.x;                  // 512 blocks
  const int bh   = id & 31;
  const int jraw = id >> 5;
  const int j    = (jraw < 8) ? jraw : 23 - jraw;   // pair (j,15-j) co-resident
  const int q0   = j * 128;
  const int qw   = q0 + w * 32;
  const int tq   = (qw + 31) >> 6;              // diagonal tile index for this wave
  const int NT   = (q0 + 128) >> 6;             // tiles this block processes

  const size_t bho = (size_t)bh * S_LEN * DHEAD;
  const bf16_t* Qb  = Qg + bho;
  const bf16_t* Kb  = Kg + bho;
  const bf16_t* VTb = VTg + bho;                // [128][2048]

  // Q fragments: lane holds Q[qw+l31][16s+8hi .. +8]
  bf16x8 qreg[8];
#pragma unroll
  for (int s = 0; s < 8; ++s)
    qreg[s] = *(const bf16x8*)(Qb + (size_t)(qw + l31) * DHEAD + s * 16 + hi * 8);

  f32x16 oacc[4];
#pragma unroll
  for (int d0 = 0; d0 < 4; ++d0)
#pragma unroll
    for (int e = 0; e < 16; ++e) oacc[d0][e] = 0.f;

  float m = -1e30f, lsum = 0.f;
  const float sc2 = 0.12751751135f;             // log2(e)/sqrt(128)

  bf16x8 kst[4], vst[4];
  // ---- prologue: stage tile 0
#pragma unroll
  for (int i = 0; i < 4; ++i) {
    const int c = tid + i * 256;
    kst[i] = *(const bf16x8*)(Kb + (size_t)(c >> 4) * DHEAD + (c & 15) * 8);
    vst[i] = *(const bf16x8*)(VTb + (size_t)(c >> 3) * S_LEN + (c & 7) * 8);
  }
#pragma unroll
  for (int i = 0; i < 4; ++i) {
    const int c  = tid + i * 256;
    const int kr = c >> 4, kc = c & 15;
    *(bf16x8*)(ldsbuf[0] + kr * 272 + ((kc ^ ((kr >> 3) & 3)) << 4)) = kst[i];
    const int vr = c >> 3, vc = c & 7;
    *(bf16x8*)(ldsbuf[0] + KLDS_BYTES + vr * 144 + ((vc ^ ((vr >> 3) & 3)) << 4)) = vst[i];
  }
  __syncthreads();

  for (int t = 0; t < NT; ++t) {
    const int kt = t << 6;
    const char* bK = ldsbuf[t & 1];
    const char* bV = bK + KLDS_BYTES;
    const bool hn = (t + 1 < NT);
    if (hn) {   // issue next-tile loads early (latency hides under compute)
#pragma unroll
      for (int i = 0; i < 4; ++i) {
        const int c = tid + i * 256;
        kst[i] = *(const bf16x8*)(Kb + (size_t)(kt + 64 + (c >> 4)) * DHEAD + (c & 15) * 8);
        vst[i] = *(const bf16x8*)(VTb + (size_t)(c >> 3) * S_LEN + kt + 64 + (c & 7) * 8);
      }
    }

    if (t <= tq) {
      // ---- swapped QK^T: D[kv][q], lane column q = l31
      f32x16 stt[2];
#pragma unroll
      for (int kh = 0; kh < 2; ++kh)
#pragma unroll
        for (int e = 0; e < 16; ++e) stt[kh][e] = 0.f;
#pragma unroll
      for (int kh = 0; kh < 2; ++kh) {
        const int row = kh * 32 + l31;
        const char* rb = bK + row * 272;
        const int swz = ((row >> 3) & 3) << 4;
#pragma unroll
        for (int s = 0; s < 8; ++s) {
          const bf16x8 kf = *(const bf16x8*)(rb + ((((s << 1) | hi) << 4) ^ swz));
          stt[kh] = MFMA32(kf, qreg[s], stt[kh]);
        }
      }
      // ---- causal mask (diagonal tile only)
      if (t == tq) {
        const int qg = qw + l31;
#pragma unroll
        for (int kh = 0; kh < 2; ++kh)
#pragma unroll
          for (int r = 0; r < 16; ++r) {
            const int kv = kt + kh * 32 + (r & 3) + 8 * (r >> 2) + 4 * hi;
            stt[kh][r] = (kv > qg) ? -1e30f : stt[kh][r];
          }
      }
      // ---- row max (in-lane + partner via shfl_xor 32)
      float pm = stt[0][0];
#pragma unroll
      for (int kh = 0; kh < 2; ++kh)
#pragma unroll
        for (int r = 0; r < 16; ++r)
          if (kh | r) pm = fmaxf(pm, stt[kh][r]);
      pm = fmaxf(pm, __shfl_xor(pm, 32));
      const float pmax = pm * sc2;
      // ---- defer-max rescale (T13, THR=8)
      if (!__all(pmax <= m + 8.f)) {
        const float mn   = fmaxf(m, pmax);
        const float corr = __builtin_amdgcn_exp2f(m - mn);
        m = mn;
        lsum *= corr;
        if (!hi) lbuf[w][l31] = corr;
#pragma unroll
        for (int r = 0; r < 16; ++r) {
          const float cr = lbuf[w][(r & 3) + 8 * (r >> 2) + 4 * hi];
#pragma unroll
          for (int d0 = 0; d0 < 4; ++d0) oacc[d0][r] *= cr;
        }
      }
      // ---- p = exp2(s*sc2 - m), row sum
      float rs = 0.f;
#pragma unroll
      for (int kh = 0; kh < 2; ++kh)
#pragma unroll
        for (int r = 0; r < 16; ++r) {
          const float p = __builtin_amdgcn_exp2f(__builtin_fmaf(stt[kh][r], sc2, -m));
          stt[kh][r] = p;
          rs += p;
        }
      rs += __shfl_xor(rs, 32);
      lsum += rs;
      // ---- pack P to bf16 A-fragments: manual pack + shfl_xor(32) + hi-select
      unsigned pw_[2][8];
#pragma unroll
      for (int kh = 0; kh < 2; ++kh)
#pragma unroll
        for (int jj = 0; jj < 8; ++jj)
          pw_[kh][jj] = pk2(stt[kh][2 * jj], stt[kh][2 * jj + 1]);
      bf16x8 pa[4];
#pragma unroll
      for (int kh = 0; kh < 2; ++kh)
#pragma unroll
        for (int c2 = 0; c2 < 2; ++c2) {
          const unsigned o0 = pw_[kh][4 * c2 + 0], o1 = pw_[kh][4 * c2 + 1];
          const unsigned o2 = pw_[kh][4 * c2 + 2], o3 = pw_[kh][4 * c2 + 3];
          const unsigned p0 = (unsigned)__shfl_xor((int)o0, 32);
          const unsigned p1 = (unsigned)__shfl_xor((int)o1, 32);
          const unsigned p2 = (unsigned)__shfl_xor((int)o2, 32);
          const unsigned p3 = (unsigned)__shfl_xor((int)o3, 32);
          union { unsigned u[4]; bf16x8 v; } uu;
          uu.u[0] = hi ? p2 : o0;
          uu.u[1] = hi ? p3 : o1;
          uu.u[2] = hi ? o2 : p0;
          uu.u[3] = hi ? o3 : p1;
          pa[2 * kh + c2] = uu.v;
        }
      // ---- PV: D[q][d] += P * V
#pragma unroll
      for (int d0 = 0; d0 < 4; ++d0) {
        const int row = d0 * 32 + l31;
        const char* rb = bV + row * 144;
        const int swz = ((row >> 3) & 3) << 4;
#pragma unroll
        for (int ks = 0; ks < 4; ++ks) {
          const bf16x8 vb = *(const bf16x8*)(rb + ((((ks << 1) | hi) << 4) ^ swz));
          oacc[d0] = MFMA32(pa[ks], vb, oacc[d0]);
        }
      }
    }
    __syncthreads();   // A: all reads of buf[(t+1)&1] (from iter t-1) complete
    if (hn) {
      char* nB = ldsbuf[(t + 1) & 1];
#pragma unroll
      for (int i = 0; i < 4; ++i) {
        const int c  = tid + i * 256;
        const int kr = c >> 4, kc = c & 15;
        *(bf16x8*)(nB + kr * 272 + ((kc ^ ((kr >> 3) & 3)) << 4)) = kst[i];
        const int vr = c >> 3, vc = c & 7;
        *(bf16x8*)(nB + KLDS_BYTES + vr * 144 + ((vc ^ ((vr >> 3) & 3)) << 4)) = vst[i];
      }
    }
    __syncthreads();   // B: staged tile visible
  }

  // ---- epilogue: normalize, write ctx [B][S][H*D] bf16
  if (!hi) lbuf[w][l31] = 1.0f / lsum;
  const int b = bh >> 4, h = bh & 15;
#pragma unroll
  for (int r = 0; r < 16; ++r) {
    const int cro = (r & 3) + 8 * (r >> 2) + 4 * hi;
    const float li = lbuf[w][cro];
    const size_t base = ((size_t)(b * S_LEN + qw + cro)) * DMODEL + h * DHEAD;
#pragma unroll
    for (int d0 = 0; d0 < 4; ++d0)
      ctx[base + d0 * 32 + l31] = (bf16_t)(oacc[d0][r] * li);
  }
}

// ------------------------------------------------------------------------- launch
extern "C" void kernel_launch(void* const* d_in, const int* in_sizes, int n_in,
                              void* d_out, int out_size, void* d_ws, size_t ws_size,
                              hipStream_t stream) {
  const float* x  = (const float*)d_in[0];
  const float* Wq = (const float*)d_in[1];
  const float* bq = (const float*)d_in[2];
  const float* Wk = (const float*)d_in[3];
  const float* bk = (const float*)d_in[4];
  const float* Wv = (const float*)d_in[5];
  const float* bv = (const float*)d_in[6];
  const float* Wo = (const float*)d_in[7];
  const float* bo = (const float*)d_in[8];

  char* ws = (char*)d_ws;
  const size_t MB = 1ull << 20;
  bf16_t* Xb  = (bf16_t*)(ws + 0);          // x bf16 (dead after gemm_qkv)
  bf16_t* VTg = (bf16_t*)(ws + 0);          // V^T reuses Xb's slot
  bf16_t* WqT = (bf16_t*)(ws + 16 * MB);
  bf16_t* WkT = (bf16_t*)(ws + 24 * MB);
  bf16_t* WvT = (bf16_t*)(ws + 32 * MB);
  bf16_t* WoT = (bf16_t*)(ws + 40 * MB);
  bf16_t* Qg  = (bf16_t*)(ws + 48 * MB);
  bf16_t* Kg  = (bf16_t*)(ws + 64 * MB);
  bf16_t* Vg  = (bf16_t*)(ws + 80 * MB);
  bf16_t* Ctx = (bf16_t*)(ws + 96 * MB);
  if (ws_size < 112 * MB) return;

  cast_kernel<<<dim3(MROWS * DMODEL / (256 * 8)), 256, 0, stream>>>(x, Xb);
  transpose_cast<<<dim3(32, 32, 4), 256, 0, stream>>>(Wq, Wk, Wv, Wo, WqT, WkT, WvT, WoT);
  gemm_qkv<<<dim3(DMODEL / 256, MROWS / 128, 3), 512, 0, stream>>>(
      Xb, WqT, WkT, WvT, bq, bk, bv, Qg, Kg, Vg);
  transpose_v<<<dim3(32, 2, 32), 256, 0, stream>>>(Vg, VTg);
  attn_kernel<<<dim3(512), 256, 0, stream>>>(Qg, Kg, VTg, Ctx);
  gemm_out<<<dim3(DMODEL / 256, MROWS / 128), 512, 0, stream>>>(Ctx, WoT, bo, (float*)d_out);
}